// Round 7
// baseline (1163.784 us; speedup 1.0000x reference)
//
#include <hip/hip_runtime.h>
#include <hip/hip_fp16.h>
#include <math.h>

#define F_IN 128
#define H 16
#define C 40
#define K_HOPS 10
#define ALPHA 0.1f
#define BN_EPS 1e-5f

#define RB 512          // nodes per bucket
#define RB_BITS 9
#define NBKT_MAX 256    // ceil(100000/512)=196
#define SRC_MASK 0x1FFFF
#define PAD 16          // node segment padding quantum (2 slots x 2 int4)
#define BKT_CAP_PAD 7712   // >= (512*15 + 16 + 15) rounded: per-bucket alloc bound

// ---------------- zero: gbcnt=0, stats=0 ----------------
__global__ void k_zero(int* __restrict__ gbcnt, float* __restrict__ stats) {
    int id = blockIdx.x * blockDim.x + threadIdx.x;
    if (id < NBKT_MAX) gbcnt[id] = 0;
    if (id < 32) stats[id] = 0.0f;
}

// ---------------- bucket counts ----------------
__global__ __launch_bounds__(256) void k_bcnt(const int* __restrict__ dst,
                                              int* __restrict__ gbcnt, int e) {
    __shared__ int hist[NBKT_MAX];
    int t = threadIdx.x;
    if (t < NBKT_MAX) hist[t] = 0;
    __syncthreads();
    int base = blockIdx.x * 4096;
    int endi = base + 4096; if (endi > e) endi = e;
    for (int i = base + t; i < endi; i += 256)
        atomicAdd(&hist[dst[i] >> RB_BITS], 1);
    __syncthreads();
    if (t < NBKT_MAX && hist[t]) atomicAdd(&gbcnt[t], hist[t]);
}

// ---------------- scans: raw bucket offsets (temp) + padded csr bases ----------------
__global__ __launch_bounds__(256) void k_bscan(const int* __restrict__ gbcnt,
                                               int* __restrict__ gboff,
                                               int* __restrict__ gcur,
                                               int* __restrict__ gcsr,
                                               int* __restrict__ nodeoff,
                                               int nbkt, int n) {
    __shared__ int sd[256];
    int t = threadIdx.x;
    int v = (t < nbkt) ? gbcnt[t] : 0;
    sd[t] = v;
    __syncthreads();
    for (int off = 1; off < 256; off <<= 1) {
        int tmp = (t >= off) ? sd[t - off] : 0;
        __syncthreads();
        sd[t] += tmp;
        __syncthreads();
    }
    if (t < nbkt) { int o = sd[t] - v; gboff[t] = o; gcur[t] = o; }
    if (t == nbkt - 1) gboff[nbkt] = sd[t];
    __syncthreads();
    // padded capacity scan for csr bases (worst-case per-node padding)
    int cap = (t < nbkt) ? ((v + RB * (PAD - 1) + PAD + PAD - 1) & ~(PAD - 1)) : 0;
    sd[t] = cap;
    __syncthreads();
    for (int off = 1; off < 256; off <<= 1) {
        int tmp = (t >= off) ? sd[t - off] : 0;
        __syncthreads();
        sd[t] += tmp;
        __syncthreads();
    }
    if (t < nbkt) gcsr[t] = sd[t] - cap;
    if (t == nbkt - 1) { gcsr[nbkt] = sd[t]; nodeoff[n] = sd[t]; }
}

// ---------------- bin edges into bucket runs (dense 4B writes) ----------------
#define BIN_CHUNK 4096
__global__ __launch_bounds__(256) void k_bin(const int* __restrict__ src,
                                             const int* __restrict__ dst,
                                             int* __restrict__ gcur,
                                             int* __restrict__ temp, int e) {
    __shared__ int hist[NBKT_MAX];
    __shared__ int lcur[NBKT_MAX];
    int t = threadIdx.x;
    if (t < NBKT_MAX) hist[t] = 0;
    __syncthreads();
    int base = blockIdx.x * BIN_CHUNK;
    int ss[16], dd[16];
#pragma unroll
    for (int i = 0; i < 16; ++i) {
        int idx = base + i * 256 + t;
        if (idx < e) {
            ss[i] = src[idx]; dd[i] = dst[idx];
            atomicAdd(&hist[dd[i] >> RB_BITS], 1);
        } else ss[i] = -1;
    }
    __syncthreads();
    if (t < NBKT_MAX) {
        int h = hist[t];
        lcur[t] = h ? atomicAdd(&gcur[t], h) : 0;
    }
    __syncthreads();
#pragma unroll
    for (int i = 0; i < 16; ++i) {
        if (ss[i] >= 0) {
            int d = dd[i];
            int b = d >> RB_BITS;
            int pos = atomicAdd(&lcur[b], 1);
            temp[pos] = ss[i] | ((d & (RB - 1)) << 17);
        }
    }
}

// ---------------- per-bucket counting sort -> padded CSR; deg->dinv, nodeoff ----------------
__global__ __launch_bounds__(256) void k_sort(const int* __restrict__ gboff,
                                              const int* __restrict__ gcsr,
                                              const int* __restrict__ temp,
                                              int* __restrict__ csr,
                                              int* __restrict__ nodeoff,
                                              float* __restrict__ dinv, int n) {
    __shared__ int hist[RB];
    __shared__ int psum[256];
    int t = threadIdx.x;
    int bkt = blockIdx.x;
    int start = gboff[bkt], endi = gboff[bkt + 1];
    hist[t] = 0; hist[t + 256] = 0;
    __syncthreads();
    for (int k = start + t; k < endi; k += 256)
        atomicAdd(&hist[temp[k] >> 17], 1);
    __syncthreads();
    int node0 = bkt * RB;
    int h0 = hist[2 * t], h1v = hist[2 * t + 1];
    int p0 = (h0 + PAD - 1) & ~(PAD - 1);
    int p1 = (h1v + PAD - 1) & ~(PAD - 1);
    if (node0 + 2 * t     < n) dinv[node0 + 2 * t]     = rsqrtf((float)(h0 + 1));
    if (node0 + 2 * t + 1 < n) dinv[node0 + 2 * t + 1] = rsqrtf((float)(h1v + 1));
    psum[t] = p0 + p1;
    __syncthreads();
    for (int off = 1; off < 256; off <<= 1) {
        int tmp = (t >= off) ? psum[t - off] : 0;
        __syncthreads();
        psum[t] += tmp;
        __syncthreads();
    }
    int pexcl = psum[t] - (p0 + p1);
    int cbase = gcsr[bkt];
    int s0 = cbase + pexcl, s1 = cbase + pexcl + p0;
    int na = node0 + 2 * t, nb2 = node0 + 2 * t + 1;
    if (na  < n) nodeoff[na]  = s0;
    if (nb2 < n) nodeoff[nb2] = s1;
    hist[2 * t] = s0; hist[2 * t + 1] = s1;
    __syncthreads();
    for (int k = start + t; k < endi; k += 256) {
        int v = temp[k];
        int dl = v >> 17;
        int pos = atomicAdd(&hist[dl], 1);
        csr[pos] = v & SRC_MASK;
    }
    __syncthreads();
    // fill within-node padding with dummy node n (zero row)
    for (int i = s0 + h0;  i < s0 + p0; ++i) csr[i] = n;
    for (int i = s1 + h1v; i < s1 + p1; ++i) csr[i] = n;
    // fill the bucket-tail gap (between sum of padded segments and bucket capacity)
    int total = psum[255];
    int bend = gcsr[bkt + 1];
    for (int i = cbase + total + t; i < bend; i += 256) csr[i] = n;
}

// ---------------- h1' = dinv .* (x @ W1) -> fp16 table (+ zero row n) ----------------
__global__ __launch_bounds__(256) void k_mm1(const float* __restrict__ x,
                                             const float* __restrict__ W1,
                                             const float* __restrict__ dinv,
                                             __half* __restrict__ h1h, int n) {
    __shared__ float xs[16 * 132];
    __shared__ float ws[128 * 16];
    int t = threadIdx.x;
    int node0 = blockIdx.x * 16;
    if (blockIdx.x == 0 && t < 16) h1h[(size_t)n * H + t] = __float2half(0.0f);
#pragma unroll
    for (int r = 0; r < 8; ++r) {
        int idx = t + r * 256;
        int nl = idx >> 7, k = idx & 127;
        int nn = node0 + nl; if (nn >= n) nn = n - 1;
        xs[nl * 132 + k] = x[(size_t)nn * F_IN + k];
        ws[idx] = W1[idx];
    }
    __syncthreads();
    int nl = t >> 4, j = t & 15;
    float acc = 0.0f;
#pragma unroll 8
    for (int k = 0; k < 128; ++k)
        acc = fmaf(xs[nl * 132 + k], ws[k * 16 + j], acc);
    int node = node0 + nl;
    if (node < n) h1h[(size_t)node * H + j] = __float2half(acc * dinv[node]);
}

// ---------------- gather conv1: 16 lanes/node (2 slots x 8 feats), int4 csr ----------------
__global__ __launch_bounds__(256) void k_gather1(const int* __restrict__ nodeoff,
                                                 const int* __restrict__ csr,
                                                 const __half* __restrict__ h1h,
                                                 const float* __restrict__ dinv,
                                                 const float* __restrict__ b1,
                                                 float* __restrict__ hout,
                                                 float* __restrict__ stats, int n) {
    __shared__ float red[4][128];
    int t = threadIdx.x;
    int idx = blockIdx.x * 256 + t;
    int node = idx >> 4;
    int jj = t & 7, slot = (t >> 3) & 1;
    float ax = 0.0f, ay = 0.0f;
    bool active = node < n;
    const __half2* h2 = reinterpret_cast<const __half2*>(h1h);
    if (active) {
        int start = nodeoff[node], endv = nodeoff[node + 1];
        const int4* csr4 = reinterpret_cast<const int4*>(csr);
        int ce = endv >> 2;
        for (int c = (start >> 2) + 2 * slot; c < ce; c += 4) {
            int4 c0 = csr4[c];
            int4 c1 = csr4[c + 1];
            __half2 g0 = h2[(size_t)c0.x * 8 + jj];
            __half2 g1 = h2[(size_t)c0.y * 8 + jj];
            __half2 g2 = h2[(size_t)c0.z * 8 + jj];
            __half2 g3 = h2[(size_t)c0.w * 8 + jj];
            __half2 g4 = h2[(size_t)c1.x * 8 + jj];
            __half2 g5 = h2[(size_t)c1.y * 8 + jj];
            __half2 g6 = h2[(size_t)c1.z * 8 + jj];
            __half2 g7 = h2[(size_t)c1.w * 8 + jj];
            float2 f0 = __half22float2(g0), f1 = __half22float2(g1);
            float2 f2 = __half22float2(g2), f3 = __half22float2(g3);
            float2 f4 = __half22float2(g4), f5 = __half22float2(g5);
            float2 f6 = __half22float2(g6), f7 = __half22float2(g7);
            ax += ((f0.x + f1.x) + (f2.x + f3.x)) + ((f4.x + f5.x) + (f6.x + f7.x));
            ay += ((f0.y + f1.y) + (f2.y + f3.y)) + ((f4.y + f5.y) + (f6.y + f7.y));
        }
    }
    ax += __shfl_xor(ax, 8);
    ay += __shfl_xor(ay, 8);
    float vx = 0.0f, vy = 0.0f;
    if (active) {
        float din = dinv[node];
        float2 self = __half22float2(h2[(size_t)node * 8 + jj]);
        vx = fmaxf(din * (ax + self.x) + b1[2 * jj], 0.0f);
        vy = fmaxf(din * (ay + self.y) + b1[2 * jj + 1], 0.0f);
        if (slot == 0)
            reinterpret_cast<float2*>(hout)[(size_t)node * 8 + jj] = make_float2(vx, vy);
    }
    if (slot == 0) {
        int ri = (t >> 4) * 8 + jj;    // 16 node-locals x 8 feats
        red[0][ri] = vx; red[1][ri] = vy; red[2][ri] = vx * vx; red[3][ri] = vy * vy;
    }
    __syncthreads();
    if (t < 8) {
        float s0 = 0.0f, s1 = 0.0f, s2 = 0.0f, s3 = 0.0f;
        for (int g = 0; g < 16; ++g) {
            int i = g * 8 + t;
            s0 += red[0][i]; s1 += red[1][i]; s2 += red[2][i]; s3 += red[3][i];
        }
        atomicAdd(&stats[2 * t], s0);
        atomicAdd(&stats[2 * t + 1], s1);
        atomicAdd(&stats[16 + 2 * t], s2);
        atomicAdd(&stats[16 + 2 * t + 1], s3);
    }
}

// ---------------- BN coefficients ----------------
__global__ void k_bncoef(float* __restrict__ stats, const float* __restrict__ gamma,
                         const float* __restrict__ beta, float nf) {
    int j = threadIdx.x;
    if (j < 16) {
        float mean = stats[j] / nf;
        float var = stats[16 + j] / nf - mean * mean;
        float a = gamma[j] * rsqrtf(var + BN_EPS);
        float c = beta[j] - mean * a;
        stats[j] = a;
        stats[16 + j] = c;
    }
}

// ---------------- BN apply + K_HOPS residual blocks -> scaled fp16 table (+ zero row) ----------------
__global__ __launch_bounds__(256) void k_hops(const float* __restrict__ h,
                                              __half* __restrict__ hh,
                                              const float* __restrict__ stats,
                                              const float* __restrict__ Wl,
                                              const float* __restrict__ bl,
                                              const float* __restrict__ dinv, int n) {
    __shared__ float wl[256], bls[16], av[16], cv[16];
    int t = threadIdx.x;
    if (blockIdx.x == 0 && t < 16) hh[(size_t)n * H + t] = __float2half(0.0f);
    wl[t] = Wl[t];
    if (t < 16) { bls[t] = bl[t]; av[t] = stats[t]; cv[t] = stats[16 + t]; }
    __syncthreads();
    int node = blockIdx.x * 256 + t;
    if (node >= n) return;
    float hr[16];
    {
        const float4* hp = reinterpret_cast<const float4*>(h + (size_t)node * H);
        float4 v0 = hp[0], v1 = hp[1], v2 = hp[2], v3 = hp[3];
        hr[0] = v0.x; hr[1] = v0.y; hr[2] = v0.z; hr[3] = v0.w;
        hr[4] = v1.x; hr[5] = v1.y; hr[6] = v1.z; hr[7] = v1.w;
        hr[8] = v2.x; hr[9] = v2.y; hr[10] = v2.z; hr[11] = v2.w;
        hr[12] = v3.x; hr[13] = v3.y; hr[14] = v3.z; hr[15] = v3.w;
    }
#pragma unroll
    for (int j = 0; j < 16; ++j) hr[j] = hr[j] * av[j] + cv[j];
    for (int it = 0; it < K_HOPS; ++it) {
        float tmp[16];
#pragma unroll
        for (int j = 0; j < 16; ++j) {
            float a = bls[j];
#pragma unroll
            for (int k = 0; k < 16; ++k) a = fmaf(hr[k], wl[k * 16 + j], a);
            tmp[j] = fmaxf(a, 0.0f);
        }
#pragma unroll
        for (int j = 0; j < 16; ++j) hr[j] = ALPHA * tmp[j] + (1.0f - ALPHA) * hr[j];
    }
    {
        float din = dinv[node];
        __half2 ph[8];
#pragma unroll
        for (int i = 0; i < 8; ++i)
            ph[i] = __floats2half2_rn(hr[2 * i] * din, hr[2 * i + 1] * din);
        int4* hp = reinterpret_cast<int4*>(hh + (size_t)node * H);
        hp[0] = *reinterpret_cast<int4*>(&ph[0]);
        hp[1] = *reinterpret_cast<int4*>(&ph[4]);
    }
}

// ---------------- gather conv2: 16 lanes/node, int4 csr; + self-loop ----------------
__global__ __launch_bounds__(256) void k_gather2(const int* __restrict__ nodeoff,
                                                 const int* __restrict__ csr,
                                                 const __half* __restrict__ hh,
                                                 const float* __restrict__ dinv,
                                                 float* __restrict__ agg, int n) {
    int t = threadIdx.x;
    int idx = blockIdx.x * 256 + t;
    int node = idx >> 4;
    int jj = t & 7, slot = (t >> 3) & 1;
    float ax = 0.0f, ay = 0.0f;
    bool active = node < n;
    const __half2* h2 = reinterpret_cast<const __half2*>(hh);
    if (active) {
        int start = nodeoff[node], endv = nodeoff[node + 1];
        const int4* csr4 = reinterpret_cast<const int4*>(csr);
        int ce = endv >> 2;
        for (int c = (start >> 2) + 2 * slot; c < ce; c += 4) {
            int4 c0 = csr4[c];
            int4 c1 = csr4[c + 1];
            __half2 g0 = h2[(size_t)c0.x * 8 + jj];
            __half2 g1 = h2[(size_t)c0.y * 8 + jj];
            __half2 g2 = h2[(size_t)c0.z * 8 + jj];
            __half2 g3 = h2[(size_t)c0.w * 8 + jj];
            __half2 g4 = h2[(size_t)c1.x * 8 + jj];
            __half2 g5 = h2[(size_t)c1.y * 8 + jj];
            __half2 g6 = h2[(size_t)c1.z * 8 + jj];
            __half2 g7 = h2[(size_t)c1.w * 8 + jj];
            float2 f0 = __half22float2(g0), f1 = __half22float2(g1);
            float2 f2 = __half22float2(g2), f3 = __half22float2(g3);
            float2 f4 = __half22float2(g4), f5 = __half22float2(g5);
            float2 f6 = __half22float2(g6), f7 = __half22float2(g7);
            ax += ((f0.x + f1.x) + (f2.x + f3.x)) + ((f4.x + f5.x) + (f6.x + f7.x));
            ay += ((f0.y + f1.y) + (f2.y + f3.y)) + ((f4.y + f5.y) + (f6.y + f7.y));
        }
    }
    ax += __shfl_xor(ax, 8);
    ay += __shfl_xor(ay, 8);
    if (active && slot == 0) {
        float din = dinv[node];
        float2 self = __half22float2(h2[(size_t)node * 8 + jj]);
        reinterpret_cast<float2*>(agg)[(size_t)node * 8 + jj] =
            make_float2(din * (ax + self.x), din * (ay + self.y));
    }
}

// ---------------- final: agg2 @ W2 + b2 -> log_softmax ----------------
__global__ __launch_bounds__(256) void k_final(const float* __restrict__ agg2,
                                               const float* __restrict__ W2,
                                               const float* __restrict__ b2,
                                               float* __restrict__ out, int n) {
    __shared__ float w2s[16 * 40];
    __shared__ float b2s[40];
    __shared__ float ostage[40 * 257];
    int t = threadIdx.x;
    for (int i = t; i < 640; i += 256) w2s[i] = W2[i];
    if (t < 40) b2s[t] = b2[t];
    __syncthreads();
    int node = blockIdx.x * 256 + t;
    if (node < n) {
        float g[16];
        const float4* ap = reinterpret_cast<const float4*>(agg2 + (size_t)node * H);
#pragma unroll
        for (int r = 0; r < 4; ++r) {
            float4 a = ap[r];
            g[r * 4 + 0] = a.x; g[r * 4 + 1] = a.y; g[r * 4 + 2] = a.z; g[r * 4 + 3] = a.w;
        }
        float z[40];
#pragma unroll
        for (int j = 0; j < 40; ++j) {
            float a = b2s[j];
#pragma unroll
            for (int k = 0; k < 16; ++k) a = fmaf(g[k], w2s[k * 40 + j], a);
            z[j] = a;
        }
        float m = z[0];
#pragma unroll
        for (int j = 1; j < 40; ++j) m = fmaxf(m, z[j]);
        float s = 0.0f;
#pragma unroll
        for (int j = 0; j < 40; ++j) s += expf(z[j] - m);
        float lse = m + logf(s);
#pragma unroll
        for (int j = 0; j < 40; ++j) ostage[j * 257 + t] = z[j] - lse;
    }
    __syncthreads();
    int nodes = n - blockIdx.x * 256;
    if (nodes > 256) nodes = 256;
    int total = nodes * 40;
    size_t base = (size_t)blockIdx.x * 256 * 40;
    for (int i = t; i < total; i += 256) {
        int nl = i / 40;
        int j = i - nl * 40;
        out[base + i] = ostage[j * 257 + nl];
    }
}

extern "C" void kernel_launch(void* const* d_in, const int* in_sizes, int n_in,
                              void* d_out, int out_size, void* d_ws, size_t ws_size,
                              hipStream_t stream) {
    const float* x     = (const float*)d_in[0];
    const int*   src   = (const int*)d_in[1];
    const int*   dst   = (const int*)d_in[2];
    const float* W1    = (const float*)d_in[3];
    const float* b1    = (const float*)d_in[4];
    const float* gamma = (const float*)d_in[5];
    const float* beta  = (const float*)d_in[6];
    const float* Wl    = (const float*)d_in[7];
    const float* bl    = (const float*)d_in[8];
    const float* W2    = (const float*)d_in[9];
    const float* b2    = (const float*)d_in[10];
    float* out = (float*)d_out;

    int n = in_sizes[0] / F_IN;   // 100000
    int e = in_sizes[1];          // 3200000
    int nbkt = (n + RB - 1) >> RB_BITS;   // 196
    int nAlign = (n + 15) & ~15;
    size_t csrCap = (size_t)e + (size_t)nbkt * BKT_CAP_PAD + 64;
    size_t hTileB = (size_t)nAlign * H * 4;                  // 6.4 MB
    size_t unionB = (size_t)e * 4;                           // temp (12.8 MB)
    if (unionB < 2 * hTileB) unionB = 2 * hTileB;            // also holds hbuf+agg2 later

    char* wsb = (char*)d_ws;
    int*    csr     = (int*)wsb;      wsb += csrCap * 4;
    char*   uni     = wsb;            wsb += unionB;
    int*    temp    = (int*)uni;                  // alive: k_bin .. k_sort
    float*  hbuf    = (float*)uni;                // alive: k_gather1 .. k_hops
    float*  agg2    = (float*)(uni + hTileB);     // alive: k_gather2 .. k_final
    int*    nodeoff = (int*)wsb;      wsb += (size_t)(nAlign + 16) * 4;
    float*  dinv    = (float*)wsb;    wsb += (size_t)nAlign * 4;
    int*    gbcnt   = (int*)wsb;      wsb += NBKT_MAX * 4;
    int*    gboff   = (int*)wsb;      wsb += (NBKT_MAX + 16) * 4;
    int*    gcur    = (int*)wsb;      wsb += NBKT_MAX * 4;
    int*    gcsr    = (int*)wsb;      wsb += (NBKT_MAX + 16) * 4;
    float*  stats   = (float*)wsb;    wsb += 64 * 4;
    __half* h1h     = (__half*)wsb;   wsb += (size_t)(nAlign + 16) * H * 2;
    __half* hh      = (__half*)wsb;   wsb += (size_t)(nAlign + 16) * H * 2;

    int nbE = (e + 4095) / 4096;   // 782

    k_zero<<<1, 256, 0, stream>>>(gbcnt, stats);
    k_bcnt<<<nbE, 256, 0, stream>>>(dst, gbcnt, e);
    k_bscan<<<1, 256, 0, stream>>>(gbcnt, gboff, gcur, gcsr, nodeoff, nbkt, n);
    k_bin<<<(e + BIN_CHUNK - 1) / BIN_CHUNK, 256, 0, stream>>>(src, dst, gcur, temp, e);
    k_sort<<<nbkt, 256, 0, stream>>>(gboff, gcsr, temp, csr, nodeoff, dinv, n);
    k_mm1<<<(n + 15) / 16, 256, 0, stream>>>(x, W1, dinv, h1h, n);
    k_gather1<<<(n * 16 + 255) / 256, 256, 0, stream>>>(nodeoff, csr, h1h, dinv, b1, hbuf, stats, n);
    k_bncoef<<<1, 16, 0, stream>>>(stats, gamma, beta, (float)n);
    k_hops<<<(n + 255) / 256, 256, 0, stream>>>(hbuf, hh, stats, Wl, bl, dinv, n);
    k_gather2<<<(n * 16 + 255) / 256, 256, 0, stream>>>(nodeoff, csr, hh, dinv, agg2, n);
    k_final<<<(n + 255) / 256, 256, 0, stream>>>(agg2, W2, b2, out, n);
}

// Round 8
// 454.603 us; speedup vs baseline: 2.5600x; 2.5600x over previous
//
#include <hip/hip_runtime.h>
#include <hip/hip_fp16.h>
#include <math.h>

#define F_IN 128
#define H 16
#define C 40
#define K_HOPS 10
#define ALPHA 0.1f
#define BN_EPS 1e-5f

#define RB 512          // nodes per bucket
#define RB_BITS 9
#define NBKT_MAX 256    // ceil(100000/512)=196
#define SRC_MASK 0x1FFFF

// ---------------- zero: gbcnt=0, stats=0 ----------------
__global__ void k_zero(int* __restrict__ gbcnt, float* __restrict__ stats) {
    int id = blockIdx.x * blockDim.x + threadIdx.x;
    if (id < NBKT_MAX) gbcnt[id] = 0;
    if (id < 32) stats[id] = 0.0f;
}

// ---------------- bucket counts ----------------
__global__ __launch_bounds__(256) void k_bcnt(const int* __restrict__ dst,
                                              int* __restrict__ gbcnt, int e) {
    __shared__ int hist[NBKT_MAX];
    int t = threadIdx.x;
    if (t < NBKT_MAX) hist[t] = 0;
    __syncthreads();
    int base = blockIdx.x * 4096;
    int endi = base + 4096; if (endi > e) endi = e;
    for (int i = base + t; i < endi; i += 256)
        atomicAdd(&hist[dst[i] >> RB_BITS], 1);
    __syncthreads();
    if (t < NBKT_MAX && hist[t]) atomicAdd(&gbcnt[t], hist[t]);
}

// ---------------- exclusive scan of bucket counts (single block) ----------------
__global__ __launch_bounds__(256) void k_bscan(const int* __restrict__ gbcnt,
                                               int* __restrict__ gboff,
                                               int* __restrict__ gcur,
                                               int* __restrict__ nodeoff,
                                               int nbkt, int n) {
    __shared__ int sd[256];
    int t = threadIdx.x;
    int v = (t < nbkt) ? gbcnt[t] : 0;
    sd[t] = v;
    __syncthreads();
    for (int off = 1; off < 256; off <<= 1) {
        int tmp = (t >= off) ? sd[t - off] : 0;
        __syncthreads();
        sd[t] += tmp;
        __syncthreads();
    }
    if (t < nbkt) { int o = sd[t] - v; gboff[t] = o; gcur[t] = o; }
    if (t == nbkt - 1) { gboff[nbkt] = sd[t]; nodeoff[n] = sd[t]; }
}

// ---------------- bin edges into bucket runs (dense 4B writes) ----------------
#define BIN_CHUNK 4096
__global__ __launch_bounds__(256) void k_bin(const int* __restrict__ src,
                                             const int* __restrict__ dst,
                                             int* __restrict__ gcur,
                                             int* __restrict__ temp, int e) {
    __shared__ int hist[NBKT_MAX];
    __shared__ int lcur[NBKT_MAX];
    int t = threadIdx.x;
    if (t < NBKT_MAX) hist[t] = 0;
    __syncthreads();
    int base = blockIdx.x * BIN_CHUNK;
    int ss[16], dd[16];
#pragma unroll
    for (int i = 0; i < 16; ++i) {
        int idx = base + i * 256 + t;
        if (idx < e) {
            ss[i] = src[idx]; dd[i] = dst[idx];
            atomicAdd(&hist[dd[i] >> RB_BITS], 1);
        } else ss[i] = -1;
    }
    __syncthreads();
    if (t < NBKT_MAX) {
        int h = hist[t];
        lcur[t] = h ? atomicAdd(&gcur[t], h) : 0;
    }
    __syncthreads();
#pragma unroll
    for (int i = 0; i < 16; ++i) {
        if (ss[i] >= 0) {
            int d = dd[i];
            int b = d >> RB_BITS;
            int pos = atomicAdd(&lcur[b], 1);
            temp[pos] = ss[i] | ((d & (RB - 1)) << 17);
        }
    }
}

// ---------------- per-bucket counting sort -> CSR (src only); deg->dinv, nodeoff ----------------
__global__ __launch_bounds__(256) void k_sort(const int* __restrict__ gboff,
                                              const int* __restrict__ temp,
                                              int* __restrict__ csr,
                                              int* __restrict__ nodeoff,
                                              float* __restrict__ dinv, int n) {
    __shared__ int hist[RB];
    __shared__ int psum[256];
    int t = threadIdx.x;
    int bkt = blockIdx.x;
    int start = gboff[bkt], endi = gboff[bkt + 1];
    hist[t] = 0; hist[t + 256] = 0;
    __syncthreads();
    for (int k = start + t; k < endi; k += 256)
        atomicAdd(&hist[temp[k] >> 17], 1);
    __syncthreads();
    int node0 = bkt * RB;
    int h0 = hist[2 * t], h1v = hist[2 * t + 1];
    if (node0 + 2 * t     < n) dinv[node0 + 2 * t]     = rsqrtf((float)(h0 + 1));
    if (node0 + 2 * t + 1 < n) dinv[node0 + 2 * t + 1] = rsqrtf((float)(h1v + 1));
    psum[t] = h0 + h1v;
    __syncthreads();
    for (int off = 1; off < 256; off <<= 1) {
        int tmp = (t >= off) ? psum[t - off] : 0;
        __syncthreads();
        psum[t] += tmp;
        __syncthreads();
    }
    int pexcl = psum[t] - (h0 + h1v);
    int off0 = pexcl, off1 = pexcl + h0;
    if (node0 + 2 * t     < n) nodeoff[node0 + 2 * t]     = start + off0;
    if (node0 + 2 * t + 1 < n) nodeoff[node0 + 2 * t + 1] = start + off1;
    hist[2 * t] = off0; hist[2 * t + 1] = off1;
    __syncthreads();
    for (int k = start + t; k < endi; k += 256) {
        int v = temp[k];
        int dl = v >> 17;
        int pos = start + atomicAdd(&hist[dl], 1);
        csr[pos] = v & SRC_MASK;
    }
}

// ---------------- h1' = dinv .* (x @ W1) -> fp16 table ----------------
__global__ __launch_bounds__(256) void k_mm1(const float* __restrict__ x,
                                             const float* __restrict__ W1,
                                             const float* __restrict__ dinv,
                                             __half* __restrict__ h1h, int n) {
    __shared__ float xs[16 * 132];
    __shared__ float ws[128 * 16];
    int t = threadIdx.x;
    int node0 = blockIdx.x * 16;
#pragma unroll
    for (int r = 0; r < 8; ++r) {
        int idx = t + r * 256;
        int nl = idx >> 7, k = idx & 127;
        int nn = node0 + nl; if (nn >= n) nn = n - 1;
        xs[nl * 132 + k] = x[(size_t)nn * F_IN + k];
        ws[idx] = W1[idx];
    }
    __syncthreads();
    int nl = t >> 4, j = t & 15;
    float acc = 0.0f;
#pragma unroll 8
    for (int k = 0; k < 128; ++k)
        acc = fmaf(xs[nl * 132 + k], ws[k * 16 + j], acc);
    int node = node0 + nl;
    if (node < n) h1h[(size_t)node * H + j] = __float2half(acc * dinv[node]);
}

// ---------------- gather conv1: 16 lanes/node (2 slots x 8 feats), predicated unroll-4 ----------------
__global__ __launch_bounds__(256) void k_gather1(const int* __restrict__ nodeoff,
                                                 const int* __restrict__ csr,
                                                 const __half* __restrict__ h1h,
                                                 const float* __restrict__ dinv,
                                                 const float* __restrict__ b1,
                                                 float* __restrict__ hout,
                                                 float* __restrict__ stats, int n) {
    __shared__ float red[4][128];
    int t = threadIdx.x;
    int idx = blockIdx.x * 256 + t;
    int node = idx >> 4;
    int jj = t & 7, slot = (t >> 3) & 1;
    float ax = 0.0f, ay = 0.0f;
    bool active = node < n;
    const __half2* h2 = reinterpret_cast<const __half2*>(h1h);
    if (active) {
        int start = nodeoff[node], endv = nodeoff[node + 1];
        int endm1 = endv - 1;
        for (int k = start + 4 * slot; k < endv; k += 8) {
            int i1 = k + 1, i2 = k + 2, i3 = k + 3;
            int s0 = csr[k];
            int s1 = csr[min(i1, endm1)];
            int s2 = csr[min(i2, endm1)];
            int s3 = csr[min(i3, endm1)];
            __half2 g0 = h2[(size_t)s0 * 8 + jj];
            __half2 g1 = h2[(size_t)s1 * 8 + jj];
            __half2 g2 = h2[(size_t)s2 * 8 + jj];
            __half2 g3 = h2[(size_t)s3 * 8 + jj];
            float2 f0 = __half22float2(g0), f1 = __half22float2(g1);
            float2 f2 = __half22float2(g2), f3 = __half22float2(g3);
            ax += f0.x; ay += f0.y;
            if (i1 < endv) { ax += f1.x; ay += f1.y; }
            if (i2 < endv) { ax += f2.x; ay += f2.y; }
            if (i3 < endv) { ax += f3.x; ay += f3.y; }
        }
    }
    ax += __shfl_xor(ax, 8);
    ay += __shfl_xor(ay, 8);
    float vx = 0.0f, vy = 0.0f;
    if (active) {
        float din = dinv[node];
        float2 self = __half22float2(h2[(size_t)node * 8 + jj]);
        vx = fmaxf(din * (ax + self.x) + b1[2 * jj], 0.0f);
        vy = fmaxf(din * (ay + self.y) + b1[2 * jj + 1], 0.0f);
        if (slot == 0)
            reinterpret_cast<float2*>(hout)[(size_t)node * 8 + jj] = make_float2(vx, vy);
    }
    if (slot == 0) {
        int ri = (t >> 4) * 8 + jj;    // 16 node-locals x 8 feats
        red[0][ri] = vx; red[1][ri] = vy; red[2][ri] = vx * vx; red[3][ri] = vy * vy;
    }
    __syncthreads();
    if (t < 8) {
        float s0 = 0.0f, s1 = 0.0f, s2 = 0.0f, s3 = 0.0f;
        for (int g = 0; g < 16; ++g) {
            int i = g * 8 + t;
            s0 += red[0][i]; s1 += red[1][i]; s2 += red[2][i]; s3 += red[3][i];
        }
        atomicAdd(&stats[2 * t], s0);
        atomicAdd(&stats[2 * t + 1], s1);
        atomicAdd(&stats[16 + 2 * t], s2);
        atomicAdd(&stats[16 + 2 * t + 1], s3);
    }
}

// ---------------- BN coefficients ----------------
__global__ void k_bncoef(float* __restrict__ stats, const float* __restrict__ gamma,
                         const float* __restrict__ beta, float nf) {
    int j = threadIdx.x;
    if (j < 16) {
        float mean = stats[j] / nf;
        float var = stats[16 + j] / nf - mean * mean;
        float a = gamma[j] * rsqrtf(var + BN_EPS);
        float c = beta[j] - mean * a;
        stats[j] = a;
        stats[16 + j] = c;
    }
}

// ---------------- BN apply + K_HOPS residual blocks -> scaled fp16 table ----------------
__global__ __launch_bounds__(256) void k_hops(const float* __restrict__ h,
                                              __half* __restrict__ hh,
                                              const float* __restrict__ stats,
                                              const float* __restrict__ Wl,
                                              const float* __restrict__ bl,
                                              const float* __restrict__ dinv, int n) {
    __shared__ float wl[256], bls[16], av[16], cv[16];
    int t = threadIdx.x;
    wl[t] = Wl[t];
    if (t < 16) { bls[t] = bl[t]; av[t] = stats[t]; cv[t] = stats[16 + t]; }
    __syncthreads();
    int node = blockIdx.x * 256 + t;
    if (node >= n) return;
    float hr[16];
    {
        const float4* hp = reinterpret_cast<const float4*>(h + (size_t)node * H);
        float4 v0 = hp[0], v1 = hp[1], v2 = hp[2], v3 = hp[3];
        hr[0] = v0.x; hr[1] = v0.y; hr[2] = v0.z; hr[3] = v0.w;
        hr[4] = v1.x; hr[5] = v1.y; hr[6] = v1.z; hr[7] = v1.w;
        hr[8] = v2.x; hr[9] = v2.y; hr[10] = v2.z; hr[11] = v2.w;
        hr[12] = v3.x; hr[13] = v3.y; hr[14] = v3.z; hr[15] = v3.w;
    }
#pragma unroll
    for (int j = 0; j < 16; ++j) hr[j] = hr[j] * av[j] + cv[j];
    for (int it = 0; it < K_HOPS; ++it) {
        float tmp[16];
#pragma unroll
        for (int j = 0; j < 16; ++j) {
            float a = bls[j];
#pragma unroll
            for (int k = 0; k < 16; ++k) a = fmaf(hr[k], wl[k * 16 + j], a);
            tmp[j] = fmaxf(a, 0.0f);
        }
#pragma unroll
        for (int j = 0; j < 16; ++j) hr[j] = ALPHA * tmp[j] + (1.0f - ALPHA) * hr[j];
    }
    {
        float din = dinv[node];
        __half2 ph[8];
#pragma unroll
        for (int i = 0; i < 8; ++i)
            ph[i] = __floats2half2_rn(hr[2 * i] * din, hr[2 * i + 1] * din);
        int4* hp = reinterpret_cast<int4*>(hh + (size_t)node * H);
        hp[0] = *reinterpret_cast<int4*>(&ph[0]);
        hp[1] = *reinterpret_cast<int4*>(&ph[4]);
    }
}

// ---------------- gather conv2: 16 lanes/node, predicated unroll-4; + self-loop ----------------
__global__ __launch_bounds__(256) void k_gather2(const int* __restrict__ nodeoff,
                                                 const int* __restrict__ csr,
                                                 const __half* __restrict__ hh,
                                                 const float* __restrict__ dinv,
                                                 float* __restrict__ agg, int n) {
    int t = threadIdx.x;
    int idx = blockIdx.x * 256 + t;
    int node = idx >> 4;
    int jj = t & 7, slot = (t >> 3) & 1;
    float ax = 0.0f, ay = 0.0f;
    bool active = node < n;
    const __half2* h2 = reinterpret_cast<const __half2*>(hh);
    if (active) {
        int start = nodeoff[node], endv = nodeoff[node + 1];
        int endm1 = endv - 1;
        for (int k = start + 4 * slot; k < endv; k += 8) {
            int i1 = k + 1, i2 = k + 2, i3 = k + 3;
            int s0 = csr[k];
            int s1 = csr[min(i1, endm1)];
            int s2 = csr[min(i2, endm1)];
            int s3 = csr[min(i3, endm1)];
            __half2 g0 = h2[(size_t)s0 * 8 + jj];
            __half2 g1 = h2[(size_t)s1 * 8 + jj];
            __half2 g2 = h2[(size_t)s2 * 8 + jj];
            __half2 g3 = h2[(size_t)s3 * 8 + jj];
            float2 f0 = __half22float2(g0), f1 = __half22float2(g1);
            float2 f2 = __half22float2(g2), f3 = __half22float2(g3);
            ax += f0.x; ay += f0.y;
            if (i1 < endv) { ax += f1.x; ay += f1.y; }
            if (i2 < endv) { ax += f2.x; ay += f2.y; }
            if (i3 < endv) { ax += f3.x; ay += f3.y; }
        }
    }
    ax += __shfl_xor(ax, 8);
    ay += __shfl_xor(ay, 8);
    if (active && slot == 0) {
        float din = dinv[node];
        float2 self = __half22float2(h2[(size_t)node * 8 + jj]);
        reinterpret_cast<float2*>(agg)[(size_t)node * 8 + jj] =
            make_float2(din * (ax + self.x), din * (ay + self.y));
    }
}

// ---------------- final: agg2 @ W2 + b2 -> log_softmax ----------------
__global__ __launch_bounds__(256) void k_final(const float* __restrict__ agg2,
                                               const float* __restrict__ W2,
                                               const float* __restrict__ b2,
                                               float* __restrict__ out, int n) {
    __shared__ float w2s[16 * 40];
    __shared__ float b2s[40];
    __shared__ float ostage[40 * 257];
    int t = threadIdx.x;
    for (int i = t; i < 640; i += 256) w2s[i] = W2[i];
    if (t < 40) b2s[t] = b2[t];
    __syncthreads();
    int node = blockIdx.x * 256 + t;
    if (node < n) {
        float g[16];
        const float4* ap = reinterpret_cast<const float4*>(agg2 + (size_t)node * H);
#pragma unroll
        for (int r = 0; r < 4; ++r) {
            float4 a = ap[r];
            g[r * 4 + 0] = a.x; g[r * 4 + 1] = a.y; g[r * 4 + 2] = a.z; g[r * 4 + 3] = a.w;
        }
        float z[40];
#pragma unroll
        for (int j = 0; j < 40; ++j) {
            float a = b2s[j];
#pragma unroll
            for (int k = 0; k < 16; ++k) a = fmaf(g[k], w2s[k * 40 + j], a);
            z[j] = a;
        }
        float m = z[0];
#pragma unroll
        for (int j = 1; j < 40; ++j) m = fmaxf(m, z[j]);
        float s = 0.0f;
#pragma unroll
        for (int j = 0; j < 40; ++j) s += expf(z[j] - m);
        float lse = m + logf(s);
#pragma unroll
        for (int j = 0; j < 40; ++j) ostage[j * 257 + t] = z[j] - lse;
    }
    __syncthreads();
    int nodes = n - blockIdx.x * 256;
    if (nodes > 256) nodes = 256;
    int total = nodes * 40;
    size_t base = (size_t)blockIdx.x * 256 * 40;
    for (int i = t; i < total; i += 256) {
        int nl = i / 40;
        int j = i - nl * 40;
        out[base + i] = ostage[j * 257 + nl];
    }
}

extern "C" void kernel_launch(void* const* d_in, const int* in_sizes, int n_in,
                              void* d_out, int out_size, void* d_ws, size_t ws_size,
                              hipStream_t stream) {
    const float* x     = (const float*)d_in[0];
    const int*   src   = (const int*)d_in[1];
    const int*   dst   = (const int*)d_in[2];
    const float* W1    = (const float*)d_in[3];
    const float* b1    = (const float*)d_in[4];
    const float* gamma = (const float*)d_in[5];
    const float* beta  = (const float*)d_in[6];
    const float* Wl    = (const float*)d_in[7];
    const float* bl    = (const float*)d_in[8];
    const float* W2    = (const float*)d_in[9];
    const float* b2    = (const float*)d_in[10];
    float* out = (float*)d_out;

    int n = in_sizes[0] / F_IN;   // 100000
    int e = in_sizes[1];          // 3200000
    int nbkt = (n + RB - 1) >> RB_BITS;   // 196
    int nAlign = (n + 15) & ~15;
    size_t hTileB = (size_t)nAlign * H * 4;                  // 6.4 MB
    size_t unionB = (size_t)e * 4;                           // temp (12.8 MB)
    if (unionB < 2 * hTileB) unionB = 2 * hTileB;            // also holds hbuf+agg2 later

    char* wsb = (char*)d_ws;
    int*    csr     = (int*)wsb;      wsb += (size_t)e * 4;
    char*   uni     = wsb;            wsb += unionB;
    int*    temp    = (int*)uni;                  // alive: k_bin .. k_sort
    float*  hbuf    = (float*)uni;                // alive: k_gather1 .. k_hops
    float*  agg2    = (float*)(uni + hTileB);     // alive: k_gather2 .. k_final
    int*    nodeoff = (int*)wsb;      wsb += (size_t)(nAlign + 16) * 4;
    float*  dinv    = (float*)wsb;    wsb += (size_t)nAlign * 4;
    int*    gbcnt   = (int*)wsb;      wsb += NBKT_MAX * 4;
    int*    gboff   = (int*)wsb;      wsb += (NBKT_MAX + 16) * 4;
    int*    gcur    = (int*)wsb;      wsb += NBKT_MAX * 4;
    float*  stats   = (float*)wsb;    wsb += 64 * 4;
    __half* h1h     = (__half*)wsb;   wsb += (size_t)(nAlign + 16) * H * 2;
    __half* hh      = (__half*)wsb;   wsb += (size_t)(nAlign + 16) * H * 2;

    int nbE = (e + 4095) / 4096;   // 782

    k_zero<<<1, 256, 0, stream>>>(gbcnt, stats);
    k_bcnt<<<nbE, 256, 0, stream>>>(dst, gbcnt, e);
    k_bscan<<<1, 256, 0, stream>>>(gbcnt, gboff, gcur, nodeoff, nbkt, n);
    k_bin<<<(e + BIN_CHUNK - 1) / BIN_CHUNK, 256, 0, stream>>>(src, dst, gcur, temp, e);
    k_sort<<<nbkt, 256, 0, stream>>>(gboff, temp, csr, nodeoff, dinv, n);
    k_mm1<<<(n + 15) / 16, 256, 0, stream>>>(x, W1, dinv, h1h, n);
    k_gather1<<<(n * 16 + 255) / 256, 256, 0, stream>>>(nodeoff, csr, h1h, dinv, b1, hbuf, stats, n);
    k_bncoef<<<1, 16, 0, stream>>>(stats, gamma, beta, (float)n);
    k_hops<<<(n + 255) / 256, 256, 0, stream>>>(hbuf, hh, stats, Wl, bl, dinv, n);
    k_gather2<<<(n * 16 + 255) / 256, 256, 0, stream>>>(nodeoff, csr, hh, dinv, agg2, n);
    k_final<<<(n + 255) / 256, 256, 0, stream>>>(agg2, W2, b2, out, n);
}

// Round 9
// 375.723 us; speedup vs baseline: 3.0974x; 1.2099x over previous
//
#include <hip/hip_runtime.h>
#include <hip/hip_fp16.h>
#include <math.h>

#define F_IN 128
#define H 16
#define C 40
#define K_HOPS 10
#define ALPHA 0.1f
#define BN_EPS 1e-5f

#define RB 512          // nodes per bucket
#define RB_BITS 9
#define NBKT_MAX 256    // ceil(100000/512)=196
#define SRC_MASK 0x1FFFF
#define PADQ 8          // node segment padded to multiple of 8 entries
#define NDUMMY 2048     // dummy zero rows spread over L2

// ---------------- zero: gbcnt=0, stats=0, dummy rows of both tables = 0 ----------------
__global__ void k_zero(int* __restrict__ gbcnt, float* __restrict__ stats,
                       __half* __restrict__ h1h, __half* __restrict__ hh, int n) {
    int id = blockIdx.x * blockDim.x + threadIdx.x;
    if (id < NBKT_MAX) gbcnt[id] = 0;
    if (id < 32) stats[id] = 0.0f;
    // NDUMMY rows x 16 halves = 64KB per table = 16384 ints
    int* z1 = (int*)(h1h + (size_t)n * H);
    int* z2 = (int*)(hh + (size_t)n * H);
    if (id < NDUMMY * H / 2) { z1[id] = 0; z2[id] = 0; }
}

// ---------------- bucket counts ----------------
__global__ __launch_bounds__(256) void k_bcnt(const int* __restrict__ dst,
                                              int* __restrict__ gbcnt, int e) {
    __shared__ int hist[NBKT_MAX];
    int t = threadIdx.x;
    if (t < NBKT_MAX) hist[t] = 0;
    __syncthreads();
    int base = blockIdx.x * 4096;
    int endi = base + 4096; if (endi > e) endi = e;
    for (int i = base + t; i < endi; i += 256)
        atomicAdd(&hist[dst[i] >> RB_BITS], 1);
    __syncthreads();
    if (t < NBKT_MAX && hist[t]) atomicAdd(&gbcnt[t], hist[t]);
}

// ---------------- scans: raw bucket offsets (temp) + padded csr bases ----------------
__global__ __launch_bounds__(256) void k_bscan(const int* __restrict__ gbcnt,
                                               int* __restrict__ gboff,
                                               int* __restrict__ gcur,
                                               int* __restrict__ gcsr, int nbkt) {
    __shared__ int sd[256];
    int t = threadIdx.x;
    int v = (t < nbkt) ? gbcnt[t] : 0;
    sd[t] = v;
    __syncthreads();
    for (int off = 1; off < 256; off <<= 1) {
        int tmp = (t >= off) ? sd[t - off] : 0;
        __syncthreads();
        sd[t] += tmp;
        __syncthreads();
    }
    if (t < nbkt) { int o = sd[t] - v; gboff[t] = o; gcur[t] = o; }
    if (t == nbkt - 1) gboff[nbkt] = sd[t];
    __syncthreads();
    // padded csr capacity: worst-case per-node padding (PADQ-1 each)
    int cap = (t < nbkt) ? ((v + RB * (PADQ - 1) + PADQ - 1) & ~(PADQ - 1)) : 0;
    sd[t] = cap;
    __syncthreads();
    for (int off = 1; off < 256; off <<= 1) {
        int tmp = (t >= off) ? sd[t - off] : 0;
        __syncthreads();
        sd[t] += tmp;
        __syncthreads();
    }
    if (t < nbkt) gcsr[t] = sd[t] - cap;
}

// ---------------- bin edges into bucket runs (dense 4B writes) ----------------
#define BIN_CHUNK 4096
__global__ __launch_bounds__(256) void k_bin(const int* __restrict__ src,
                                             const int* __restrict__ dst,
                                             int* __restrict__ gcur,
                                             int* __restrict__ temp, int e) {
    __shared__ int hist[NBKT_MAX];
    __shared__ int lcur[NBKT_MAX];
    int t = threadIdx.x;
    if (t < NBKT_MAX) hist[t] = 0;
    __syncthreads();
    int base = blockIdx.x * BIN_CHUNK;
    int ss[16], dd[16];
#pragma unroll
    for (int i = 0; i < 16; ++i) {
        int idx = base + i * 256 + t;
        if (idx < e) {
            ss[i] = src[idx]; dd[i] = dst[idx];
            atomicAdd(&hist[dd[i] >> RB_BITS], 1);
        } else ss[i] = -1;
    }
    __syncthreads();
    if (t < NBKT_MAX) {
        int h = hist[t];
        lcur[t] = h ? atomicAdd(&gcur[t], h) : 0;
    }
    __syncthreads();
#pragma unroll
    for (int i = 0; i < 16; ++i) {
        if (ss[i] >= 0) {
            int d = dd[i];
            int b = d >> RB_BITS;
            int pos = atomicAdd(&lcur[b], 1);
            temp[pos] = ss[i] | ((d & (RB - 1)) << 17);
        }
    }
}

// ---------------- per-bucket counting sort -> padded CSR; deg->dinv, nodestart/nodeend ----------------
__global__ __launch_bounds__(256) void k_sort(const int* __restrict__ gboff,
                                              const int* __restrict__ gcsr,
                                              const int* __restrict__ temp,
                                              int* __restrict__ csr,
                                              int* __restrict__ nodestart,
                                              int* __restrict__ nodeend,
                                              float* __restrict__ dinv, int n) {
    __shared__ int hist[RB];
    __shared__ int psum[256];
    int t = threadIdx.x;
    int bkt = blockIdx.x;
    int start = gboff[bkt], endi = gboff[bkt + 1];
    hist[t] = 0; hist[t + 256] = 0;
    __syncthreads();
    for (int k = start + t; k < endi; k += 256)
        atomicAdd(&hist[temp[k] >> 17], 1);
    __syncthreads();
    int node0 = bkt * RB;
    int h0 = hist[2 * t], h1v = hist[2 * t + 1];
    int p0 = (h0 + PADQ - 1) & ~(PADQ - 1);
    int p1 = (h1v + PADQ - 1) & ~(PADQ - 1);
    int na = node0 + 2 * t, nb = na + 1;
    if (na < n) dinv[na] = rsqrtf((float)(h0 + 1));
    if (nb < n) dinv[nb] = rsqrtf((float)(h1v + 1));
    psum[t] = p0 + p1;
    __syncthreads();
    for (int off = 1; off < 256; off <<= 1) {
        int tmp = (t >= off) ? psum[t - off] : 0;
        __syncthreads();
        psum[t] += tmp;
        __syncthreads();
    }
    int pexcl = psum[t] - (p0 + p1);
    int cbase = gcsr[bkt];
    int s0 = cbase + pexcl, s1 = s0 + p0;
    if (na < n) { nodestart[na] = s0; nodeend[na] = s0 + p0; }
    if (nb < n) { nodestart[nb] = s1; nodeend[nb] = s1 + p1; }
    hist[2 * t] = s0; hist[2 * t + 1] = s1;
    __syncthreads();
    for (int k = start + t; k < endi; k += 256) {
        int v = temp[k];
        int dl = v >> 17;
        int pos = atomicAdd(&hist[dl], 1);
        csr[pos] = v & SRC_MASK;
    }
    __syncthreads();
    // pad with distinct dummy zero rows (no shared hotspot, no predication needed)
    for (int i = s0 + h0;  i < s0 + p0; ++i) csr[i] = n + (i & (NDUMMY - 1));
    for (int i = s1 + h1v; i < s1 + p1; ++i) csr[i] = n + (i & (NDUMMY - 1));
}

// ---------------- h1' = dinv .* (x @ W1) -> fp16 table ----------------
__global__ __launch_bounds__(256) void k_mm1(const float* __restrict__ x,
                                             const float* __restrict__ W1,
                                             const float* __restrict__ dinv,
                                             __half* __restrict__ h1h, int n) {
    __shared__ float xs[16 * 132];
    __shared__ float ws[128 * 16];
    int t = threadIdx.x;
    int node0 = blockIdx.x * 16;
#pragma unroll
    for (int r = 0; r < 8; ++r) {
        int idx = t + r * 256;
        int nl = idx >> 7, k = idx & 127;
        int nn = node0 + nl; if (nn >= n) nn = n - 1;
        xs[nl * 132 + k] = x[(size_t)nn * F_IN + k];
        ws[idx] = W1[idx];
    }
    __syncthreads();
    int nl = t >> 4, j = t & 15;
    float acc = 0.0f;
#pragma unroll 8
    for (int k = 0; k < 128; ++k)
        acc = fmaf(xs[nl * 132 + k], ws[k * 16 + j], acc);
    int node = node0 + nl;
    if (node < n) h1h[(size_t)node * H + j] = __float2half(acc * dinv[node]);
}

// ---------------- gather conv1: 8 lanes/node, int4 csr, 8 gathers/iter; + bias + ReLU + BN stats ----------------
__global__ __launch_bounds__(256) void k_gather1(const int* __restrict__ nodestart,
                                                 const int* __restrict__ nodeend,
                                                 const int* __restrict__ csr,
                                                 const __half* __restrict__ h1h,
                                                 const float* __restrict__ dinv,
                                                 const float* __restrict__ b1,
                                                 float* __restrict__ hout,
                                                 float* __restrict__ stats, int n) {
    __shared__ float red[4][256];
    int t = threadIdx.x;
    int idx = blockIdx.x * 256 + t;
    int node = idx >> 3, jj = idx & 7;
    float ax = 0.0f, ay = 0.0f, vx = 0.0f, vy = 0.0f;
    const __half2* h2 = reinterpret_cast<const __half2*>(h1h);
    if (node < n) {
        int c = nodestart[node] >> 2, ce = nodeend[node] >> 2;
        const int4* csr4 = reinterpret_cast<const int4*>(csr);
        for (; c < ce; c += 2) {
            int4 a = csr4[c];
            int4 b = csr4[c + 1];
            __half2 g0 = h2[(size_t)a.x * 8 + jj];
            __half2 g1 = h2[(size_t)a.y * 8 + jj];
            __half2 g2 = h2[(size_t)a.z * 8 + jj];
            __half2 g3 = h2[(size_t)a.w * 8 + jj];
            __half2 g4 = h2[(size_t)b.x * 8 + jj];
            __half2 g5 = h2[(size_t)b.y * 8 + jj];
            __half2 g6 = h2[(size_t)b.z * 8 + jj];
            __half2 g7 = h2[(size_t)b.w * 8 + jj];
            float2 f0 = __half22float2(g0), f1 = __half22float2(g1);
            float2 f2 = __half22float2(g2), f3 = __half22float2(g3);
            float2 f4 = __half22float2(g4), f5 = __half22float2(g5);
            float2 f6 = __half22float2(g6), f7 = __half22float2(g7);
            ax += ((f0.x + f1.x) + (f2.x + f3.x)) + ((f4.x + f5.x) + (f6.x + f7.x));
            ay += ((f0.y + f1.y) + (f2.y + f3.y)) + ((f4.y + f5.y) + (f6.y + f7.y));
        }
        float din = dinv[node];
        float2 self = __half22float2(h2[(size_t)node * 8 + jj]);
        vx = fmaxf(din * (ax + self.x) + b1[2 * jj], 0.0f);
        vy = fmaxf(din * (ay + self.y) + b1[2 * jj + 1], 0.0f);
        reinterpret_cast<float2*>(hout)[(size_t)node * 8 + jj] = make_float2(vx, vy);
    }
    red[0][t] = vx; red[1][t] = vy; red[2][t] = vx * vx; red[3][t] = vy * vy;
    __syncthreads();
    if (t < 8) {
        float s0 = 0.0f, s1 = 0.0f, s2 = 0.0f, s3 = 0.0f;
        for (int g = 0; g < 32; ++g) {
            int i = g * 8 + t;
            s0 += red[0][i]; s1 += red[1][i]; s2 += red[2][i]; s3 += red[3][i];
        }
        atomicAdd(&stats[2 * t], s0);
        atomicAdd(&stats[2 * t + 1], s1);
        atomicAdd(&stats[16 + 2 * t], s2);
        atomicAdd(&stats[16 + 2 * t + 1], s3);
    }
}

// ---------------- BN coefficients ----------------
__global__ void k_bncoef(float* __restrict__ stats, const float* __restrict__ gamma,
                         const float* __restrict__ beta, float nf) {
    int j = threadIdx.x;
    if (j < 16) {
        float mean = stats[j] / nf;
        float var = stats[16 + j] / nf - mean * mean;
        float a = gamma[j] * rsqrtf(var + BN_EPS);
        float c = beta[j] - mean * a;
        stats[j] = a;
        stats[16 + j] = c;
    }
}

// ---------------- BN apply + K_HOPS residual blocks -> scaled fp16 table ----------------
__global__ __launch_bounds__(256) void k_hops(const float* __restrict__ h,
                                              __half* __restrict__ hh,
                                              const float* __restrict__ stats,
                                              const float* __restrict__ Wl,
                                              const float* __restrict__ bl,
                                              const float* __restrict__ dinv, int n) {
    __shared__ float wl[256], bls[16], av[16], cv[16];
    int t = threadIdx.x;
    wl[t] = Wl[t];
    if (t < 16) { bls[t] = bl[t]; av[t] = stats[t]; cv[t] = stats[16 + t]; }
    __syncthreads();
    int node = blockIdx.x * 256 + t;
    if (node >= n) return;
    float hr[16];
    {
        const float4* hp = reinterpret_cast<const float4*>(h + (size_t)node * H);
        float4 v0 = hp[0], v1 = hp[1], v2 = hp[2], v3 = hp[3];
        hr[0] = v0.x; hr[1] = v0.y; hr[2] = v0.z; hr[3] = v0.w;
        hr[4] = v1.x; hr[5] = v1.y; hr[6] = v1.z; hr[7] = v1.w;
        hr[8] = v2.x; hr[9] = v2.y; hr[10] = v2.z; hr[11] = v2.w;
        hr[12] = v3.x; hr[13] = v3.y; hr[14] = v3.z; hr[15] = v3.w;
    }
#pragma unroll
    for (int j = 0; j < 16; ++j) hr[j] = hr[j] * av[j] + cv[j];
    for (int it = 0; it < K_HOPS; ++it) {
        float tmp[16];
#pragma unroll
        for (int j = 0; j < 16; ++j) {
            float a = bls[j];
#pragma unroll
            for (int k = 0; k < 16; ++k) a = fmaf(hr[k], wl[k * 16 + j], a);
            tmp[j] = fmaxf(a, 0.0f);
        }
#pragma unroll
        for (int j = 0; j < 16; ++j) hr[j] = ALPHA * tmp[j] + (1.0f - ALPHA) * hr[j];
    }
    {
        float din = dinv[node];
        __half2 ph[8];
#pragma unroll
        for (int i = 0; i < 8; ++i)
            ph[i] = __floats2half2_rn(hr[2 * i] * din, hr[2 * i + 1] * din);
        int4* hp = reinterpret_cast<int4*>(hh + (size_t)node * H);
        hp[0] = *reinterpret_cast<int4*>(&ph[0]);
        hp[1] = *reinterpret_cast<int4*>(&ph[4]);
    }
}

// ---------------- gather conv2: 8 lanes/node, int4 csr; + self-loop ----------------
__global__ __launch_bounds__(256) void k_gather2(const int* __restrict__ nodestart,
                                                 const int* __restrict__ nodeend,
                                                 const int* __restrict__ csr,
                                                 const __half* __restrict__ hh,
                                                 const float* __restrict__ dinv,
                                                 float* __restrict__ agg, int n) {
    int t = threadIdx.x;
    int idx = blockIdx.x * 256 + t;
    int node = idx >> 3, jj = idx & 7;
    if (node >= n) return;
    const __half2* h2 = reinterpret_cast<const __half2*>(hh);
    float ax = 0.0f, ay = 0.0f;
    int c = nodestart[node] >> 2, ce = nodeend[node] >> 2;
    const int4* csr4 = reinterpret_cast<const int4*>(csr);
    for (; c < ce; c += 2) {
        int4 a = csr4[c];
        int4 b = csr4[c + 1];
        __half2 g0 = h2[(size_t)a.x * 8 + jj];
        __half2 g1 = h2[(size_t)a.y * 8 + jj];
        __half2 g2 = h2[(size_t)a.z * 8 + jj];
        __half2 g3 = h2[(size_t)a.w * 8 + jj];
        __half2 g4 = h2[(size_t)b.x * 8 + jj];
        __half2 g5 = h2[(size_t)b.y * 8 + jj];
        __half2 g6 = h2[(size_t)b.z * 8 + jj];
        __half2 g7 = h2[(size_t)b.w * 8 + jj];
        float2 f0 = __half22float2(g0), f1 = __half22float2(g1);
        float2 f2 = __half22float2(g2), f3 = __half22float2(g3);
        float2 f4 = __half22float2(g4), f5 = __half22float2(g5);
        float2 f6 = __half22float2(g6), f7 = __half22float2(g7);
        ax += ((f0.x + f1.x) + (f2.x + f3.x)) + ((f4.x + f5.x) + (f6.x + f7.x));
        ay += ((f0.y + f1.y) + (f2.y + f3.y)) + ((f4.y + f5.y) + (f6.y + f7.y));
    }
    float din = dinv[node];
    float2 self = __half22float2(h2[(size_t)node * 8 + jj]);
    reinterpret_cast<float2*>(agg)[(size_t)node * 8 + jj] =
        make_float2(din * (ax + self.x), din * (ay + self.y));
}

// ---------------- final: agg2 @ W2 + b2 -> log_softmax ----------------
__global__ __launch_bounds__(256) void k_final(const float* __restrict__ agg2,
                                               const float* __restrict__ W2,
                                               const float* __restrict__ b2,
                                               float* __restrict__ out, int n) {
    __shared__ float w2s[16 * 40];
    __shared__ float b2s[40];
    __shared__ float ostage[40 * 257];
    int t = threadIdx.x;
    for (int i = t; i < 640; i += 256) w2s[i] = W2[i];
    if (t < 40) b2s[t] = b2[t];
    __syncthreads();
    int node = blockIdx.x * 256 + t;
    if (node < n) {
        float g[16];
        const float4* ap = reinterpret_cast<const float4*>(agg2 + (size_t)node * H);
#pragma unroll
        for (int r = 0; r < 4; ++r) {
            float4 a = ap[r];
            g[r * 4 + 0] = a.x; g[r * 4 + 1] = a.y; g[r * 4 + 2] = a.z; g[r * 4 + 3] = a.w;
        }
        float z[40];
#pragma unroll
        for (int j = 0; j < 40; ++j) {
            float a = b2s[j];
#pragma unroll
            for (int k = 0; k < 16; ++k) a = fmaf(g[k], w2s[k * 40 + j], a);
            z[j] = a;
        }
        float m = z[0];
#pragma unroll
        for (int j = 1; j < 40; ++j) m = fmaxf(m, z[j]);
        float s = 0.0f;
#pragma unroll
        for (int j = 0; j < 40; ++j) s += expf(z[j] - m);
        float lse = m + logf(s);
#pragma unroll
        for (int j = 0; j < 40; ++j) ostage[j * 257 + t] = z[j] - lse;
    }
    __syncthreads();
    int nodes = n - blockIdx.x * 256;
    if (nodes > 256) nodes = 256;
    int total = nodes * 40;
    size_t base = (size_t)blockIdx.x * 256 * 40;
    for (int i = t; i < total; i += 256) {
        int nl = i / 40;
        int j = i - nl * 40;
        out[base + i] = ostage[j * 257 + nl];
    }
}

extern "C" void kernel_launch(void* const* d_in, const int* in_sizes, int n_in,
                              void* d_out, int out_size, void* d_ws, size_t ws_size,
                              hipStream_t stream) {
    const float* x     = (const float*)d_in[0];
    const int*   src   = (const int*)d_in[1];
    const int*   dst   = (const int*)d_in[2];
    const float* W1    = (const float*)d_in[3];
    const float* b1    = (const float*)d_in[4];
    const float* gamma = (const float*)d_in[5];
    const float* beta  = (const float*)d_in[6];
    const float* Wl    = (const float*)d_in[7];
    const float* bl    = (const float*)d_in[8];
    const float* W2    = (const float*)d_in[9];
    const float* b2    = (const float*)d_in[10];
    float* out = (float*)d_out;

    int n = in_sizes[0] / F_IN;   // 100000
    int e = in_sizes[1];          // 3200000
    int nbkt = (n + RB - 1) >> RB_BITS;   // 196
    int nAlign = (n + 15) & ~15;
    size_t csrCap = (size_t)e + (size_t)nAlign * (PADQ - 1) + 4096;   // padded CSR bound
    size_t hTileB = (size_t)nAlign * H * 4;                  // 6.4 MB
    size_t unionB = (size_t)e * 4;                           // temp (12.8 MB)
    if (unionB < 2 * hTileB) unionB = 2 * hTileB;            // also holds hbuf+agg2 later

    char* wsb = (char*)d_ws;
    int*    csr      = (int*)wsb;      wsb += csrCap * 4;
    char*   uni      = wsb;            wsb += unionB;
    int*    temp     = (int*)uni;                  // alive: k_bin .. k_sort
    float*  hbuf     = (float*)uni;                // alive: k_gather1 .. k_hops
    float*  agg2     = (float*)(uni + hTileB);     // alive: k_gather2 .. k_final
    int*    nodestart= (int*)wsb;      wsb += (size_t)(nAlign + 16) * 4;
    int*    nodeend  = (int*)wsb;      wsb += (size_t)(nAlign + 16) * 4;
    float*  dinv     = (float*)wsb;    wsb += (size_t)nAlign * 4;
    int*    gbcnt    = (int*)wsb;      wsb += NBKT_MAX * 4;
    int*    gboff    = (int*)wsb;      wsb += (NBKT_MAX + 16) * 4;
    int*    gcur     = (int*)wsb;      wsb += NBKT_MAX * 4;
    int*    gcsr     = (int*)wsb;      wsb += (NBKT_MAX + 16) * 4;
    float*  stats    = (float*)wsb;    wsb += 64 * 4;
    __half* h1h      = (__half*)wsb;   wsb += (size_t)(nAlign + NDUMMY + 16) * H * 2;
    __half* hh       = (__half*)wsb;   wsb += (size_t)(nAlign + NDUMMY + 16) * H * 2;

    int nbE = (e + 4095) / 4096;   // 782

    k_zero<<<64, 256, 0, stream>>>(gbcnt, stats, h1h, hh, n);
    k_bcnt<<<nbE, 256, 0, stream>>>(dst, gbcnt, e);
    k_bscan<<<1, 256, 0, stream>>>(gbcnt, gboff, gcur, gcsr, nbkt);
    k_bin<<<(e + BIN_CHUNK - 1) / BIN_CHUNK, 256, 0, stream>>>(src, dst, gcur, temp, e);
    k_sort<<<nbkt, 256, 0, stream>>>(gboff, gcsr, temp, csr, nodestart, nodeend, dinv, n);
    k_mm1<<<(n + 15) / 16, 256, 0, stream>>>(x, W1, dinv, h1h, n);
    k_gather1<<<(n * 8 + 255) / 256, 256, 0, stream>>>(nodestart, nodeend, csr, h1h, dinv, b1, hbuf, stats, n);
    k_bncoef<<<1, 16, 0, stream>>>(stats, gamma, beta, (float)n);
    k_hops<<<(n + 255) / 256, 256, 0, stream>>>(hbuf, hh, stats, Wl, bl, dinv, n);
    k_gather2<<<(n * 8 + 255) / 256, 256, 0, stream>>>(nodestart, nodeend, csr, hh, dinv, agg2, n);
    k_final<<<(n + 255) / 256, 256, 0, stream>>>(agg2, W2, b2, out, n);
}